// Round 8
// baseline (27.536 us; speedup 1.0000x reference)
//
#include <hip/hip_runtime.h>
#include <math.h>

// DTLN part-2 in THREE kernels (2 boundaries).
// K1: enc = enc_W@y1 (256 blk) + ph1 = Whh1@h1_in + b (64 blk) + ph2 = Whh2@h2_in + b (64 blk).
// K2: LN (redundant/blk) + z1 gate-rows (gate-row ownership) -> h1, c1.  128 blk.
// K3: per-block redundant z2 -> h2 -> est (Wih2 256KB + dense 128KB panels,
//     L2-shared by 16 blk/XCD, 512 waves hide latency), then dec rows 8/blk. 128 blk.

#define FRAME 1024
#define ENC 256
#define HID 128

__device__ __forceinline__ float sigmoidf_(float x) { return 1.0f / (1.0f + __expf(-x)); }
__device__ __forceinline__ float tanhf_(float x) { return 2.0f * sigmoidf_(2.0f * x) - 1.0f; }

__device__ __forceinline__ float wred(float v) {
#pragma unroll
    for (int o = 32; o > 0; o >>= 1) v += __shfl_xor(v, o);
    return v;  // all lanes
}

// ---- K1: enc rows + input-only recurrent partials ----
__global__ __launch_bounds__(256) void k_enc(
    const float* __restrict__ enc_W, const float* __restrict__ y1,
    const float* __restrict__ Whh1, const float* __restrict__ bih1,
    const float* __restrict__ bhh1, const float* __restrict__ h1_in,
    const float* __restrict__ Whh2, const float* __restrict__ bih2,
    const float* __restrict__ bhh2, const float* __restrict__ h2_in,
    float* __restrict__ enc_g, float* __restrict__ ph1, float* __restrict__ ph2) {
    const int t = threadIdx.x, lane = t & 63, w = t >> 6, bid = blockIdx.x;
    if (bid < 256) {
        // enc row bid: 4 waves split K=1024
        const float4 a = reinterpret_cast<const float4*>(enc_W + bid * FRAME)[t];
        const float4 b = reinterpret_cast<const float4*>(y1)[t];
        float p = a.x * b.x + a.y * b.y + a.z * b.z + a.w * b.w;
        p = wred(p);
        __shared__ float red[4];
        if (lane == 0) red[w] = p;
        __syncthreads();
        if (t == 0) enc_g[bid] = red[0] + red[1] + red[2] + red[3];
    } else if (bid < 320) {
        // ph1 rows: 8/block, 2/wave, K=128 (one float2/lane)
        const int pb = bid - 256;
#pragma unroll
        for (int j = 0; j < 2; ++j) {
            const int r = pb * 8 + w * 2 + j;
            const float2 a = reinterpret_cast<const float2*>(Whh1 + r * HID)[lane];
            const float2 b = reinterpret_cast<const float2*>(h1_in)[lane];
            float p = a.x * b.x + a.y * b.y;
            p = wred(p);
            if (lane == 0) ph1[r] = p + bih1[r] + bhh1[r];
        }
    } else {
        // ph2 rows
        const int pb = bid - 320;
#pragma unroll
        for (int j = 0; j < 2; ++j) {
            const int r = pb * 8 + w * 2 + j;
            const float2 a = reinterpret_cast<const float2*>(Whh2 + r * HID)[lane];
            const float2 b = reinterpret_cast<const float2*>(h2_in)[lane];
            float p = a.x * b.x + a.y * b.y;
            p = wred(p);
            if (lane == 0) ph2[r] = p + bih2[r] + bhh2[r];
        }
    }
}

// ---- K2: LN + z1 gate-rows of unit b -> h1, c1. 128 blocks ----
__global__ __launch_bounds__(256) void k_z1(
    const float* __restrict__ enc_g, const float* __restrict__ gamma,
    const float* __restrict__ beta, const float* __restrict__ Wih1,
    const float* __restrict__ ph1, const float* __restrict__ c1_in,
    float* __restrict__ h1_g, float* __restrict__ out) {
    const int t = threadIdx.x, lane = t & 63, w = t >> 6, b = blockIdx.x;
    __shared__ __align__(16) float encN[ENC];
    __shared__ float red[8];
    __shared__ float zsh[4];

    const int r = b + HID * w;  // gate w of unit b
    const float4 wa = reinterpret_cast<const float4*>(Wih1 + r * ENC)[lane];
    const float ph = ph1[r];

    const float e = enc_g[t];
    const float s1 = wred(e);
    const float s2 = wred(e * e);
    if (lane == 0) { red[w] = s1; red[4 + w] = s2; }
    __syncthreads();
    const float mean = (red[0] + red[1] + red[2] + red[3]) * (1.f / ENC);
    const float var  = (red[4] + red[5] + red[6] + red[7]) * (1.f / ENC) - mean * mean;
    const float inv  = rsqrtf(var + 1e-7f);
    encN[t] = (e - mean) * inv * gamma[t] + beta[t];
    __syncthreads();

    const float4 xa = reinterpret_cast<const float4*>(encN)[lane];
    float p = wa.x * xa.x + wa.y * xa.y + wa.z * xa.z + wa.w * xa.w;
    p = wred(p);
    if (lane == 0) zsh[w] = p + ph;
    __syncthreads();
    if (t == 0) {
        const float i = sigmoidf_(zsh[0]);
        const float f = sigmoidf_(zsh[1]);
        const float g = tanhf_(zsh[2]);
        const float o = sigmoidf_(zsh[3]);
        const float c = f * c1_in[b] + i * g;
        const float h = o * tanhf_(c);
        h1_g[b] = h;
        out[FRAME + b] = h;
        out[FRAME + HID + b] = c;
    }
}

// ---- K3: redundant z2 -> h2 -> est per block, then dec rows 8/block. 128 blocks ----
__global__ __launch_bounds__(256) void k_rest(
    const float* __restrict__ h1_g, const float* __restrict__ Wih2,
    const float* __restrict__ ph2, const float* __restrict__ c2_in,
    const float* __restrict__ dense_W, const float* __restrict__ dense_b,
    const float* __restrict__ enc_g, const float* __restrict__ dec_W,
    float* __restrict__ out) {
    const int t = threadIdx.x, lane = t & 63, w = t >> 6, bid = blockIdx.x;
    const int sub = lane >> 2, q = lane & 3;

    __shared__ __align__(16) float h1s[HID];
    __shared__ __align__(16) float h2s[HID];
    __shared__ __align__(16) float zz[4 * HID];
    __shared__ __align__(16) float encL[ENC];
    __shared__ __align__(16) float es[ENC];

    if (t < HID) h1s[t] = h1_g[t];
    if (t < ENC) encL[t] = enc_g[t];
    __syncthreads();

    // z2: all 512 rows per block. wave w owns rows [w*128, w*128+128), 8 passes x 16 rows.
    {
        const float4* x4 = reinterpret_cast<const float4*>(h1s);
        float4 xv[8];
#pragma unroll
        for (int j = 0; j < 8; ++j) xv[j] = x4[q * 8 + j];
#pragma unroll
        for (int p = 0; p < 8; ++p) {
            const int r = w * 128 + p * 16 + sub;
            const float4* W4 = reinterpret_cast<const float4*>(Wih2 + r * HID);
            float4 acc = {0.f, 0.f, 0.f, 0.f};
#pragma unroll
            for (int j = 0; j < 8; ++j) {
                const float4 a = W4[q * 8 + j];
                acc.x += a.x * xv[j].x; acc.y += a.y * xv[j].y;
                acc.z += a.z * xv[j].z; acc.w += a.w * xv[j].w;
            }
            float s = acc.x + acc.y + acc.z + acc.w;
            s += __shfl_xor(s, 1); s += __shfl_xor(s, 2);
            if (q == 0) zz[r] = s + ph2[r];
        }
    }
    __syncthreads();

    // gates2 -> h2 (full, block-local)
    if (t < HID) {
        const float i = sigmoidf_(zz[t]);
        const float f = sigmoidf_(zz[HID + t]);
        const float g = tanhf_(zz[2 * HID + t]);
        const float o = sigmoidf_(zz[3 * HID + t]);
        const float c = f * c2_in[t] + i * g;
        const float h = o * tanhf_(c);
        h2s[t] = h;
        if (bid == 0) { out[FRAME + 2 * HID + t] = h; out[FRAME + 3 * HID + t] = c; }
    }
    __syncthreads();

    // est: 256 rows per block. wave w owns rows [w*64, w*64+64), 4 passes x 16 rows.
    {
        const float4* x4 = reinterpret_cast<const float4*>(h2s);
        float4 xv[8];
#pragma unroll
        for (int j = 0; j < 8; ++j) xv[j] = x4[q * 8 + j];
#pragma unroll
        for (int p = 0; p < 4; ++p) {
            const int r = w * 64 + p * 16 + sub;
            const float4* W4 = reinterpret_cast<const float4*>(dense_W + r * HID);
            float4 acc = {0.f, 0.f, 0.f, 0.f};
#pragma unroll
            for (int j = 0; j < 8; ++j) {
                const float4 a = W4[q * 8 + j];
                acc.x += a.x * xv[j].x; acc.y += a.y * xv[j].y;
                acc.z += a.z * xv[j].z; acc.w += a.w * xv[j].w;
            }
            float s = acc.x + acc.y + acc.z + acc.w;
            s += __shfl_xor(s, 1); s += __shfl_xor(s, 2);
            if (q == 0) es[r] = sigmoidf_(s + dense_b[r]) * encL[r];
        }
    }
    __syncthreads();

    // dec: 8 rows/block, 2/wave, full-wave K=256 dots
    {
        const float4 xe = reinterpret_cast<const float4*>(es)[lane];
#pragma unroll
        for (int j = 0; j < 2; ++j) {
            const int r = bid * 8 + w * 2 + j;
            const float4 a = reinterpret_cast<const float4*>(dec_W + r * ENC)[lane];
            float s = a.x * xe.x + a.y * xe.y + a.z * xe.z + a.w * xe.w;
            s = wred(s);
            if (lane == 0) out[r] = s;
        }
    }
}

extern "C" void kernel_launch(void* const* d_in, const int* in_sizes, int n_in,
                              void* d_out, int out_size, void* d_ws, size_t ws_size,
                              hipStream_t stream) {
    const float* y1      = (const float*)d_in[0];
    const float* h1_in   = (const float*)d_in[1];
    const float* c1_in   = (const float*)d_in[2];
    const float* h2_in   = (const float*)d_in[3];
    const float* c2_in   = (const float*)d_in[4];
    const float* enc_W   = (const float*)d_in[5];
    const float* gamma   = (const float*)d_in[6];
    const float* beta    = (const float*)d_in[7];
    const float* Wih1    = (const float*)d_in[8];
    const float* Whh1    = (const float*)d_in[9];
    const float* bih1    = (const float*)d_in[10];
    const float* bhh1    = (const float*)d_in[11];
    const float* Wih2    = (const float*)d_in[12];
    const float* Whh2    = (const float*)d_in[13];
    const float* bih2    = (const float*)d_in[14];
    const float* bhh2    = (const float*)d_in[15];
    const float* dense_W = (const float*)d_in[16];
    const float* dense_b = (const float*)d_in[17];
    const float* dec_W   = (const float*)d_in[18];

    float* out   = (float*)d_out;
    float* ws    = (float*)d_ws;
    float* enc_g = ws;           // 256
    float* ph1   = ws + 256;     // 512
    float* ph2   = ws + 768;     // 512
    float* h1_g  = ws + 1280;    // 128

    k_enc <<<384, 256, 0, stream>>>(enc_W, y1, Whh1, bih1, bhh1, h1_in,
                                    Whh2, bih2, bhh2, h2_in, enc_g, ph1, ph2);
    k_z1  <<<128, 256, 0, stream>>>(enc_g, gamma, beta, Wih1, ph1, c1_in, h1_g, out);
    k_rest<<<128, 256, 0, stream>>>(h1_g, Wih2, ph2, c2_in, dense_W, dense_b,
                                    enc_g, dec_W, out);
}

// Round 9
// 19.439 us; speedup vs baseline: 1.4165x; 1.4165x over previous
//
#include <hip/hip_runtime.h>
#include <math.h>

// DTLN part-2, 4 kernels (3 boundaries). vs R7's 5: k_mask is eliminated by
// rank-1 accumulation of the dense matvec into a padded accumulator (macc)
// from k_z2's gate-row-owner blocks (block b owns h2[b]), via relaxed
// device-scope f32 atomicAdd (one add per line per block; 256 lines parallel).
// k_dec then finishes est = sigmoid(macc+db)*enc redundantly (cheap) + dec rows.
// macc zeroing is done by k_z1 blocks (z1->z2 boundary orders it). No memset.

#define FRAME 1024
#define ENC 256
#define HID 128
#define MSTRIDE 32  // floats between macc slots (128B = one cache line per row)

__device__ __forceinline__ float sigmoidf_(float x) { return 1.0f / (1.0f + __expf(-x)); }
__device__ __forceinline__ float tanhf_(float x) { return 2.0f * sigmoidf_(2.0f * x) - 1.0f; }

__device__ __forceinline__ float wred(float v) {
#pragma unroll
    for (int o = 32; o > 0; o >>= 1) v += __shfl_xor(v, o);
    return v;  // all lanes
}

// ---- K1: enc = enc_W @ y1. 256 blocks, 1 row/block, 4 waves split K=1024 ----
__global__ __launch_bounds__(256) void k_enc(const float* __restrict__ enc_W,
                                             const float* __restrict__ y1,
                                             float* __restrict__ enc_g) {
    const int t = threadIdx.x, lane = t & 63, w = t >> 6, row = blockIdx.x;
    const float4 a = reinterpret_cast<const float4*>(enc_W + row * FRAME)[t];
    const float4 b = reinterpret_cast<const float4*>(y1)[t];
    float p = a.x * b.x + a.y * b.y + a.z * b.z + a.w * b.w;
    p = wred(p);
    __shared__ float red[4];
    if (lane == 0) red[w] = p;
    __syncthreads();
    if (t == 0) enc_g[row] = red[0] + red[1] + red[2] + red[3];
}

// ---- K2: LN (cheap redundant) + z1 gate-rows of unit b -> h1,c1; zero macc ----
__global__ __launch_bounds__(256) void k_z1(
    const float* __restrict__ enc_g, const float* __restrict__ gamma,
    const float* __restrict__ beta, const float* __restrict__ Wih1,
    const float* __restrict__ Whh1, const float* __restrict__ bih1,
    const float* __restrict__ bhh1, const float* __restrict__ h1_in,
    const float* __restrict__ c1_in, float* __restrict__ h1_g,
    float* __restrict__ macc, float* __restrict__ out) {
    const int t = threadIdx.x, lane = t & 63, w = t >> 6, b = blockIdx.x;
    __shared__ __align__(16) float encN[ENC];
    __shared__ __align__(16) float hs[HID];
    __shared__ float red[8];
    __shared__ float zsh[4];

    const int r = b + HID * w;  // gate w of unit b
    const float4 wa = reinterpret_cast<const float4*>(Wih1 + r * ENC)[lane];
    const float2 wb = reinterpret_cast<const float2*>(Whh1 + r * HID)[lane];
    const float bias = bih1[r] + bhh1[r];

    // zero the macc accumulator slots (32 blocks x 8 rows = 256 rows exactly once)
    if (b < 32 && t < 8) macc[(b * 8 + t) * MSTRIDE] = 0.0f;

    const float e = enc_g[t];
    const float s1 = wred(e);
    const float s2 = wred(e * e);
    if (lane == 0) { red[w] = s1; red[4 + w] = s2; }
    if (t < HID) hs[t] = h1_in[t];
    __syncthreads();
    const float mean = (red[0] + red[1] + red[2] + red[3]) * (1.f / ENC);
    const float var  = (red[4] + red[5] + red[6] + red[7]) * (1.f / ENC) - mean * mean;
    const float inv  = rsqrtf(var + 1e-7f);
    encN[t] = (e - mean) * inv * gamma[t] + beta[t];
    __syncthreads();

    const float4 xa = reinterpret_cast<const float4*>(encN)[lane];
    const float2 xb = reinterpret_cast<const float2*>(hs)[lane];
    float p = wa.x * xa.x + wa.y * xa.y + wa.z * xa.z + wa.w * xa.w
            + wb.x * xb.x + wb.y * xb.y;
    p = wred(p);
    if (lane == 0) zsh[w] = p + bias;
    __syncthreads();
    if (t == 0) {
        const float i = sigmoidf_(zsh[0]);
        const float f = sigmoidf_(zsh[1]);
        const float g = tanhf_(zsh[2]);
        const float o = sigmoidf_(zsh[3]);
        const float c = f * c1_in[b] + i * g;
        const float h = o * tanhf_(c);
        h1_g[b] = h;
        out[FRAME + b] = h;
        out[FRAME + HID + b] = c;
    }
}

// ---- K3: z2 gate-rows -> h2,c2 + rank-1 dense contribution into macc ----
__global__ __launch_bounds__(256) void k_z2(
    const float* __restrict__ h1_g, const float* __restrict__ h2_in,
    const float* __restrict__ Wih2, const float* __restrict__ Whh2,
    const float* __restrict__ bih2, const float* __restrict__ bhh2,
    const float* __restrict__ c2_in, const float* __restrict__ dense_W,
    float* __restrict__ macc, float* __restrict__ out) {
    const int t = threadIdx.x, lane = t & 63, w = t >> 6, b = blockIdx.x;
    __shared__ __align__(16) float hA[HID];
    __shared__ __align__(16) float hB[HID];
    __shared__ float zsh[4];
    __shared__ float h2sh;

    const int r = b + HID * w;
    const float2 wa = reinterpret_cast<const float2*>(Wih2 + r * HID)[lane];
    const float2 wb = reinterpret_cast<const float2*>(Whh2 + r * HID)[lane];
    const float bias = bih2[r] + bhh2[r];
    // input-only column gather for the rank-1 update: dense_W[t, b]
    const float dcol = dense_W[t * HID + b];

    if (t < HID) { hA[t] = h1_g[t]; hB[t] = h2_in[t]; }
    __syncthreads();
    const float2 xa = reinterpret_cast<const float2*>(hA)[lane];
    const float2 xb = reinterpret_cast<const float2*>(hB)[lane];
    float p = wa.x * xa.x + wa.y * xa.y + wb.x * xb.x + wb.y * xb.y;
    p = wred(p);
    if (lane == 0) zsh[w] = p + bias;
    __syncthreads();
    if (t == 0) {
        const float i = sigmoidf_(zsh[0]);
        const float f = sigmoidf_(zsh[1]);
        const float g = tanhf_(zsh[2]);
        const float o = sigmoidf_(zsh[3]);
        const float c = f * c2_in[b] + i * g;
        const float h = o * tanhf_(c);
        h2sh = h;
        out[FRAME + 2 * HID + b] = h;
        out[FRAME + 3 * HID + b] = c;
    }
    __syncthreads();
    // rank-1: macc[t] += dense_W[t,b] * h2[b]   (one add per line per block)
    atomicAdd(&macc[t * MSTRIDE], dcol * h2sh);
}

// ---- K4: est finish (redundant, cheap) + dec rows. 256 blocks, 4 rows each ----
__global__ __launch_bounds__(256) void k_dec(
    const float* __restrict__ dec_W, const float* __restrict__ macc,
    const float* __restrict__ dense_b, const float* __restrict__ enc_g,
    float* __restrict__ out) {
    const int t = threadIdx.x, lane = t & 63, w = t >> 6;
    __shared__ __align__(16) float es[ENC];
    const float m = macc[t * MSTRIDE];
    es[t] = sigmoidf_(m + dense_b[t]) * enc_g[t];
    __syncthreads();
    const int r = blockIdx.x * 4 + w;
    const float4 a = reinterpret_cast<const float4*>(dec_W + r * ENC)[lane];
    const float4 bb = reinterpret_cast<const float4*>(es)[lane];
    float p = a.x * bb.x + a.y * bb.y + a.z * bb.z + a.w * bb.w;
    p = wred(p);
    if (lane == 0) out[r] = p;
}

extern "C" void kernel_launch(void* const* d_in, const int* in_sizes, int n_in,
                              void* d_out, int out_size, void* d_ws, size_t ws_size,
                              hipStream_t stream) {
    const float* y1      = (const float*)d_in[0];
    const float* h1_in   = (const float*)d_in[1];
    const float* c1_in   = (const float*)d_in[2];
    const float* h2_in   = (const float*)d_in[3];
    const float* c2_in   = (const float*)d_in[4];
    const float* enc_W   = (const float*)d_in[5];
    const float* gamma   = (const float*)d_in[6];
    const float* beta    = (const float*)d_in[7];
    const float* Wih1    = (const float*)d_in[8];
    const float* Whh1    = (const float*)d_in[9];
    const float* bih1    = (const float*)d_in[10];
    const float* bhh1    = (const float*)d_in[11];
    const float* Wih2    = (const float*)d_in[12];
    const float* Whh2    = (const float*)d_in[13];
    const float* bih2    = (const float*)d_in[14];
    const float* bhh2    = (const float*)d_in[15];
    const float* dense_W = (const float*)d_in[16];
    const float* dense_b = (const float*)d_in[17];
    const float* dec_W   = (const float*)d_in[18];

    float* out   = (float*)d_out;
    float* ws    = (float*)d_ws;
    float* enc_g = ws;            // 256 floats
    float* h1_g  = ws + 256;      // 128 floats
    float* macc  = ws + 512;      // 256*MSTRIDE floats = 32KB, line-padded

    k_enc<<<256, 256, 0, stream>>>(enc_W, y1, enc_g);
    k_z1 <<<128, 256, 0, stream>>>(enc_g, gamma, beta, Wih1, Whh1, bih1, bhh1,
                                   h1_in, c1_in, h1_g, macc, out);
    k_z2 <<<128, 256, 0, stream>>>(h1_g, h2_in, Wih2, Whh2, bih2, bhh2,
                                   c2_in, dense_W, macc, out);
    k_dec<<<256, 256, 0, stream>>>(dec_W, macc, dense_b, enc_g, out);
}

// Round 10
// 18.150 us; speedup vs baseline: 1.5171x; 1.0710x over previous
//
#include <hip/hip_runtime.h>
#include <math.h>

// DTLN part-2, 4 kernels (3 boundaries = minimum for the 4-stage sequential
// dependency chain enc -> h1 -> h2 -> est/dec without in-kernel sync).
// vs R9: k_z2 uses 32 blocks x 4 units (atomic contention 128->32 adds/line),
// and the input-only recurrent partials ph1/ph2 + macc zeroing are hoisted
// into K1's spare blocks, shedding Whh loads from the critical path.

#define FRAME 1024
#define ENC 256
#define HID 128
#define MSTRIDE 32  // floats between macc slots (one 128B line per row)

__device__ __forceinline__ float sigmoidf_(float x) { return 1.0f / (1.0f + __expf(-x)); }
__device__ __forceinline__ float tanhf_(float x) { return 2.0f * sigmoidf_(2.0f * x) - 1.0f; }

__device__ __forceinline__ float wred(float v) {
#pragma unroll
    for (int o = 32; o > 0; o >>= 1) v += __shfl_xor(v, o);
    return v;  // all lanes
}

// ---- K1: enc rows (256 blk) + ph1/ph2 partials (64 blk) + macc zero ----
__global__ __launch_bounds__(256) void k_enc(
    const float* __restrict__ enc_W, const float* __restrict__ y1,
    const float* __restrict__ Whh1, const float* __restrict__ bih1,
    const float* __restrict__ bhh1, const float* __restrict__ h1_in,
    const float* __restrict__ Whh2, const float* __restrict__ bih2,
    const float* __restrict__ bhh2, const float* __restrict__ h2_in,
    float* __restrict__ enc_g, float* __restrict__ ph1,
    float* __restrict__ ph2, float* __restrict__ macc) {
    const int t = threadIdx.x, lane = t & 63, w = t >> 6, bid = blockIdx.x;
    if (bid < 256) {
        const float4 a = reinterpret_cast<const float4*>(enc_W + bid * FRAME)[t];
        const float4 b = reinterpret_cast<const float4*>(y1)[t];
        float p = a.x * b.x + a.y * b.y + a.z * b.z + a.w * b.w;
        p = wred(p);
        __shared__ float red[4];
        if (lane == 0) red[w] = p;
        __syncthreads();
        if (t == 0) enc_g[bid] = red[0] + red[1] + red[2] + red[3];
    } else {
        const bool is1 = bid < 288;
        const int pb = is1 ? bid - 256 : bid - 288;   // 32 blocks each side
        const float* Whh = is1 ? Whh1 : Whh2;
        const float* bi  = is1 ? bih1 : bih2;
        const float* bh  = is1 ? bhh1 : bhh2;
        const float* hin = is1 ? h1_in : h2_in;
        float* dst       = is1 ? ph1 : ph2;
        const float2 hv = reinterpret_cast<const float2*>(hin)[lane];
#pragma unroll
        for (int j = 0; j < 4; ++j) {
            const int r = pb * 16 + w * 4 + j;        // 16 rows/block, 512 total
            const float2 a = reinterpret_cast<const float2*>(Whh + r * HID)[lane];
            float p = a.x * hv.x + a.y * hv.y;
            p = wred(p);
            if (lane == 0) dst[r] = p + bi[r] + bh[r];
        }
        if (!is1 && t < 8) macc[(pb * 8 + t) * MSTRIDE] = 0.0f;  // 32*8 = 256 slots
    }
}

// ---- K2: LN (cheap redundant) + z1 gate-rows of unit b -> h1,c1. 128 blk ----
__global__ __launch_bounds__(256) void k_z1(
    const float* __restrict__ enc_g, const float* __restrict__ gamma,
    const float* __restrict__ beta, const float* __restrict__ Wih1,
    const float* __restrict__ ph1, const float* __restrict__ c1_in,
    float* __restrict__ h1_g, float* __restrict__ out) {
    const int t = threadIdx.x, lane = t & 63, w = t >> 6, b = blockIdx.x;
    __shared__ __align__(16) float encN[ENC];
    __shared__ float red[8];
    __shared__ float zsh[4];

    const int r = b + HID * w;  // gate w of unit b
    const float4 wa = reinterpret_cast<const float4*>(Wih1 + r * ENC)[lane];
    const float ph = ph1[r];

    const float e = enc_g[t];
    const float s1 = wred(e);
    const float s2 = wred(e * e);
    if (lane == 0) { red[w] = s1; red[4 + w] = s2; }
    __syncthreads();
    const float mean = (red[0] + red[1] + red[2] + red[3]) * (1.f / ENC);
    const float var  = (red[4] + red[5] + red[6] + red[7]) * (1.f / ENC) - mean * mean;
    const float inv  = rsqrtf(var + 1e-7f);
    encN[t] = (e - mean) * inv * gamma[t] + beta[t];
    __syncthreads();

    const float4 xa = reinterpret_cast<const float4*>(encN)[lane];
    float p = wa.x * xa.x + wa.y * xa.y + wa.z * xa.z + wa.w * xa.w;
    p = wred(p);
    if (lane == 0) zsh[w] = p + ph;
    __syncthreads();
    if (t == 0) {
        const float i = sigmoidf_(zsh[0]);
        const float f = sigmoidf_(zsh[1]);
        const float g = tanhf_(zsh[2]);
        const float o = sigmoidf_(zsh[3]);
        const float c = f * c1_in[b] + i * g;
        const float h = o * tanhf_(c);
        h1_g[b] = h;
        out[FRAME + b] = h;
        out[FRAME + HID + b] = c;
    }
}

// ---- K3: z2 + gates2 for 4 units/block + rank-4 macc atomics. 32 blocks ----
__global__ __launch_bounds__(256) void k_z2(
    const float* __restrict__ h1_g, const float* __restrict__ Wih2,
    const float* __restrict__ ph2, const float* __restrict__ c2_in,
    const float* __restrict__ dense_W, float* __restrict__ macc,
    float* __restrict__ out) {
    const int t = threadIdx.x, lane = t & 63, w = t >> 6, bid = blockIdx.x;
    const int ub = bid * 4;  // 4 consecutive units per block
    __shared__ __align__(16) float hA[HID];
    __shared__ float zsh[16];   // [gate m][unit j]
    __shared__ float h2sh[4];

    // input-only loads issued first
    const float4 dcol = *reinterpret_cast<const float4*>(dense_W + t * HID + ub);
    float2 wa[4]; float phv[4];
#pragma unroll
    for (int j = 0; j < 4; ++j) {
        const int r = (ub + j) + HID * w;   // gate w of unit ub+j
        wa[j] = reinterpret_cast<const float2*>(Wih2 + r * HID)[lane];
        phv[j] = ph2[r];
    }

    if (t < HID) hA[t] = h1_g[t];
    __syncthreads();
    const float2 xa = reinterpret_cast<const float2*>(hA)[lane];
#pragma unroll
    for (int j = 0; j < 4; ++j) {
        float p = wa[j].x * xa.x + wa[j].y * xa.y;
        p = wred(p);
        if (lane == 0) zsh[w * 4 + j] = p + phv[j];
    }
    __syncthreads();
    if (t < 4) {
        const int u = ub + t;
        const float i = sigmoidf_(zsh[0 * 4 + t]);
        const float f = sigmoidf_(zsh[1 * 4 + t]);
        const float g = tanhf_(zsh[2 * 4 + t]);
        const float o = sigmoidf_(zsh[3 * 4 + t]);
        const float c = f * c2_in[u] + i * g;
        const float h = o * tanhf_(c);
        h2sh[t] = h;
        out[FRAME + 2 * HID + u] = h;
        out[FRAME + 3 * HID + u] = c;
    }
    __syncthreads();
    // rank-4: macc[t] += dense_W[t, ub..ub+3] . h2[ub..ub+3]  (32 adds/line)
    const float contrib = dcol.x * h2sh[0] + dcol.y * h2sh[1]
                        + dcol.z * h2sh[2] + dcol.w * h2sh[3];
    atomicAdd(&macc[t * MSTRIDE], contrib);
}

// ---- K4: est finish (redundant, cheap) + dec rows. 256 blocks, 4 rows each ----
__global__ __launch_bounds__(256) void k_dec(
    const float* __restrict__ dec_W, const float* __restrict__ macc,
    const float* __restrict__ dense_b, const float* __restrict__ enc_g,
    float* __restrict__ out) {
    const int t = threadIdx.x, lane = t & 63, w = t >> 6;
    __shared__ __align__(16) float es[ENC];
    const float m = macc[t * MSTRIDE];
    es[t] = sigmoidf_(m + dense_b[t]) * enc_g[t];
    __syncthreads();
    const int r = blockIdx.x * 4 + w;
    const float4 a = reinterpret_cast<const float4*>(dec_W + r * ENC)[lane];
    const float4 bb = reinterpret_cast<const float4*>(es)[lane];
    float p = a.x * bb.x + a.y * bb.y + a.z * bb.z + a.w * bb.w;
    p = wred(p);
    if (lane == 0) out[r] = p;
}

extern "C" void kernel_launch(void* const* d_in, const int* in_sizes, int n_in,
                              void* d_out, int out_size, void* d_ws, size_t ws_size,
                              hipStream_t stream) {
    const float* y1      = (const float*)d_in[0];
    const float* h1_in   = (const float*)d_in[1];
    const float* c1_in   = (const float*)d_in[2];
    const float* h2_in   = (const float*)d_in[3];
    const float* c2_in   = (const float*)d_in[4];
    const float* enc_W   = (const float*)d_in[5];
    const float* gamma   = (const float*)d_in[6];
    const float* beta    = (const float*)d_in[7];
    const float* Wih1    = (const float*)d_in[8];
    const float* Whh1    = (const float*)d_in[9];
    const float* bih1    = (const float*)d_in[10];
    const float* bhh1    = (const float*)d_in[11];
    const float* Wih2    = (const float*)d_in[12];
    const float* Whh2    = (const float*)d_in[13];
    const float* bih2    = (const float*)d_in[14];
    const float* bhh2    = (const float*)d_in[15];
    const float* dense_W = (const float*)d_in[16];
    const float* dense_b = (const float*)d_in[17];
    const float* dec_W   = (const float*)d_in[18];

    float* out   = (float*)d_out;
    float* ws    = (float*)d_ws;
    float* enc_g = ws;             // 256
    float* h1_g  = ws + 256;       // 128
    float* macc  = ws + 512;       // 256*32 = 8192 (line-padded)
    float* ph1   = ws + 8704;      // 512
    float* ph2   = ws + 9216;      // 512

    k_enc<<<320, 256, 0, stream>>>(enc_W, y1, Whh1, bih1, bhh1, h1_in,
                                   Whh2, bih2, bhh2, h2_in, enc_g, ph1, ph2, macc);
    k_z1 <<<128, 256, 0, stream>>>(enc_g, gamma, beta, Wih1, ph1, c1_in, h1_g, out);
    k_z2 <<<32, 256, 0, stream>>>(h1_g, Wih2, ph2, c2_in, dense_W, macc, out);
    k_dec<<<256, 256, 0, stream>>>(dec_W, macc, dense_b, enc_g, out);
}